// Round 1
// baseline (128.599 us; speedup 1.0000x reference)
//
#include <hip/hip_runtime.h>
#include <math.h>

#define NB   128
#define CCH  512
#define HW   784      // 28*28
#define NCLS 1000
#define TOT4 12845056 // 128*512*784/4

// K1: pooled[n*C+c] = mean over HW. One wave per channel, 4 waves/block.
__global__ __launch_bounds__(256) void k_pool(const float* __restrict__ feat,
                                              float* __restrict__ pooled) {
    int wv = threadIdx.x >> 6, lane = threadIdx.x & 63;
    int ch = blockIdx.x * 4 + wv;              // flat (n,c), < 65536
    const float* src = feat + (size_t)ch * HW;
    float s = 0.f;
#pragma unroll
    for (int it = 0; it < 3; ++it) {           // 3 * 256 floats
        float4 v = *reinterpret_cast<const float4*>(src + it * 256 + lane * 4);
        s += v.x + v.y + v.z + v.w;
    }
    if (lane < 4) {                            // last 16 floats
        float4 v = *reinterpret_cast<const float4*>(src + 768 + lane * 4);
        s += v.x + v.y + v.z + v.w;
    }
#pragma unroll
    for (int o = 32; o; o >>= 1) s += __shfl_down(s, o, 64);
    if (lane == 0) pooled[ch] = s * (1.0f / 784.0f);
}

// K2: pred[n][cls] = dot(pooled[n], w[cls]) + b[cls]. One wave per (n,cls).
__global__ __launch_bounds__(256) void k_linear(const float* __restrict__ pooled,
                                                const float* __restrict__ w,
                                                const float* __restrict__ b,
                                                float* __restrict__ out) {
    int wv = threadIdx.x >> 6, lane = threadIdx.x & 63;
    int idx = blockIdx.x * 4 + wv;             // < 128000
    int n = idx / NCLS, cls = idx - n * NCLS;
    const float* wr = w + (size_t)cls * CCH;
    const float* pr = pooled + (size_t)n * CCH;
    float4 a0 = *reinterpret_cast<const float4*>(wr + lane * 8);
    float4 a1 = *reinterpret_cast<const float4*>(wr + lane * 8 + 4);
    float4 p0 = *reinterpret_cast<const float4*>(pr + lane * 8);
    float4 p1 = *reinterpret_cast<const float4*>(pr + lane * 8 + 4);
    float s = a0.x * p0.x + a0.y * p0.y + a0.z * p0.z + a0.w * p0.w
            + a1.x * p1.x + a1.y * p1.y + a1.z * p1.z + a1.w * p1.w;
#pragma unroll
    for (int o = 32; o; o >>= 1) s += __shfl_down(s, o, 64);
    if (lane == 0) out[idx] = s + b[cls];
}

// K3: mask[n][c] = softmax_c(1 + g/||g|| * sqrt(C)/2), g = w[y[n]]*pooled[n].
// One 512-thread block per n.
__global__ __launch_bounds__(512) void k_mask(const float* __restrict__ pooled,
                                              const float* __restrict__ w,
                                              const int* __restrict__ y,
                                              float* __restrict__ mask) {
    __shared__ float red[8];
    __shared__ float bc;
    int n = blockIdx.x;
    int c = threadIdx.x;                       // 0..511
    int lane = c & 63, wv = c >> 6;
    int cls = y[n];
    float g = w[(size_t)cls * CCH + c] * pooled[(size_t)n * CCH + c];

    // --- sum of squares ---
    float ss = g * g;
#pragma unroll
    for (int o = 32; o; o >>= 1) ss += __shfl_down(ss, o, 64);
    if (lane == 0) red[wv] = ss;
    __syncthreads();
    if (c == 0) { float t = 0.f; for (int i = 0; i < 8; ++i) t += red[i]; bc = sqrtf(t); }
    __syncthreads();
    float vv = 1.0f + g * (11.313708498984761f / bc);   // sqrt(512)/2 = 11.3137...
    __syncthreads();

    // --- max ---
    float mx = vv;
#pragma unroll
    for (int o = 32; o; o >>= 1) mx = fmaxf(mx, __shfl_down(mx, o, 64));
    if (lane == 0) red[wv] = mx;
    __syncthreads();
    if (c == 0) { float t = red[0]; for (int i = 1; i < 8; ++i) t = fmaxf(t, red[i]); bc = t; }
    __syncthreads();
    float e = expf(vv - bc);
    __syncthreads();

    // --- sum of exp ---
    float se = e;
#pragma unroll
    for (int o = 32; o; o >>= 1) se += __shfl_down(se, o, 64);
    if (lane == 0) red[wv] = se;
    __syncthreads();
    if (c == 0) { float t = 0.f; for (int i = 0; i < 8; ++i) t += red[i]; bc = t; }
    __syncthreads();
    mask[(size_t)n * CCH + c] = e / bc;
}

// K4: out = feat * mask[channel]. One float4 per thread.
__global__ __launch_bounds__(256) void k_apply(const float* __restrict__ feat,
                                               const float* __restrict__ mask,
                                               float* __restrict__ out) {
    unsigned int i = blockIdx.x * 256u + threadIdx.x;   // float4 index, < TOT4
    unsigned int ch = i / 196u;                         // 784/4 float4 per channel
    float m = mask[ch];
    float4 v = reinterpret_cast<const float4*>(feat)[i];
    v.x *= m; v.y *= m; v.z *= m; v.w *= m;
    reinterpret_cast<float4*>(out)[i] = v;
}

extern "C" void kernel_launch(void* const* d_in, const int* in_sizes, int n_in,
                              void* d_out, int out_size, void* d_ws, size_t ws_size,
                              hipStream_t stream) {
    const float* feat = (const float*)d_in[0];
    const int*   y    = (const int*)d_in[1];
    const float* w    = (const float*)d_in[2];
    const float* b    = (const float*)d_in[3];

    float* out_feat = (float*)d_out;                       // 128*512*28*28
    float* out_pred = out_feat + (size_t)NB * CCH * HW;    // 128*1000

    float* pooled = (float*)d_ws;                          // 65536 floats
    float* maskp  = pooled + NB * CCH;                     // 65536 floats

    k_pool  <<<(NB * CCH) / 4, 256, 0, stream>>>(feat, pooled);
    k_linear<<<(NB * NCLS) / 4, 256, 0, stream>>>(pooled, w, b, out_pred);
    k_mask  <<<NB, 512, 0, stream>>>(pooled, w, y, maskp);
    k_apply <<<TOT4 / 256, 256, 0, stream>>>(feat, maskp, out_feat);
}

// Round 3
// 106.055 us; speedup vs baseline: 1.2126x; 1.2126x over previous
//
#include <hip/hip_runtime.h>
#include <math.h>

#define NB   128
#define CCH  512
#define HW   784      // 28*28
#define NCLS 1000
#define TOT4 12845056 // 128*512*784/4

typedef float f32x4 __attribute__((ext_vector_type(4)));

// K1: pooled[n*C+c] = mean over HW. One wave per channel, 4 waves/block.
__global__ __launch_bounds__(256) void k_pool(const float* __restrict__ feat,
                                              float* __restrict__ pooled) {
    int wv = threadIdx.x >> 6, lane = threadIdx.x & 63;
    int ch = blockIdx.x * 4 + wv;              // flat (n,c), < 65536
    const float* src = feat + (size_t)ch * HW;
    float s = 0.f;
#pragma unroll
    for (int it = 0; it < 3; ++it) {           // 3 * 256 floats
        f32x4 v = *reinterpret_cast<const f32x4*>(src + it * 256 + lane * 4);
        s += v.x + v.y + v.z + v.w;
    }
    if (lane < 4) {                            // last 16 floats
        f32x4 v = *reinterpret_cast<const f32x4*>(src + 768 + lane * 4);
        s += v.x + v.y + v.z + v.w;
    }
#pragma unroll
    for (int o = 32; o; o >>= 1) s += __shfl_down(s, o, 64);
    if (lane == 0) pooled[ch] = s * (1.0f / 784.0f);
}

// K2+K3 fused.
// Blocks [0, 4000): linear. Each block = 4 cls (one per wave) x 8 n (LDS-staged).
//   w-row traffic: 1000 rows x 16 n-groups x 2KB = 32 MB (was 256 MB).
// Blocks [4000, 4128): mask for n = blockIdx.x - 4000 (256 thr x 2 channels).
#define LIN_BLOCKS 4000
__global__ __launch_bounds__(256) void k_head(const float* __restrict__ pooled,
                                              const float* __restrict__ w,
                                              const float* __restrict__ b,
                                              const int* __restrict__ y,
                                              float* __restrict__ pred,
                                              float* __restrict__ mask) {
    __shared__ float sp[4096];                 // 16 KB: pooled tile OR reduction scratch
    int t = threadIdx.x, lane = t & 63, wv = t >> 6;

    if (blockIdx.x < LIN_BLOCKS) {
        int cb = blockIdx.x % 250;             // cls group
        int nb = blockIdx.x / 250;             // n group (8 images)
        const float* pbase = pooled + (size_t)nb * 8 * CCH;
#pragma unroll
        for (int k = 0; k < 4; ++k)            // 4096 floats, 16/thread
            *reinterpret_cast<f32x4*>(sp + k * 1024 + t * 4) =
                *reinterpret_cast<const f32x4*>(pbase + k * 1024 + t * 4);
        __syncthreads();

        int cls = cb * 4 + wv;
        const float* wr = w + (size_t)cls * CCH;
        f32x4 a0 = *reinterpret_cast<const f32x4*>(wr + lane * 8);
        f32x4 a1 = *reinterpret_cast<const f32x4*>(wr + lane * 8 + 4);
        float bias = b[cls];
        float s[8];
#pragma unroll
        for (int nn = 0; nn < 8; ++nn) {
            f32x4 p0 = *reinterpret_cast<const f32x4*>(sp + nn * CCH + lane * 8);
            f32x4 p1 = *reinterpret_cast<const f32x4*>(sp + nn * CCH + lane * 8 + 4);
            s[nn] = a0.x * p0.x + a0.y * p0.y + a0.z * p0.z + a0.w * p0.w
                  + a1.x * p1.x + a1.y * p1.y + a1.z * p1.z + a1.w * p1.w;
        }
#pragma unroll
        for (int nn = 0; nn < 8; ++nn) {
            float v = s[nn];
#pragma unroll
            for (int o = 32; o; o >>= 1) v += __shfl_down(v, o, 64);
            if (lane == 0) pred[(size_t)(nb * 8 + nn) * NCLS + cls] = v + bias;
        }
    } else {
        int n = blockIdx.x - LIN_BLOCKS;
        int cls = y[n];
        const float* wr = w + (size_t)cls * CCH;
        const float* pr = pooled + (size_t)n * CCH;
        float g0 = wr[t] * pr[t];
        float g1 = wr[t + 256] * pr[t + 256];

        // sum of squares -> norm
        float ss = g0 * g0 + g1 * g1;
#pragma unroll
        for (int o = 32; o; o >>= 1) ss += __shfl_down(ss, o, 64);
        if (lane == 0) sp[wv] = ss;
        __syncthreads();
        if (t == 0) sp[8] = sqrtf(sp[0] + sp[1] + sp[2] + sp[3]);
        __syncthreads();
        float inv = 11.313708498984761f / sp[8];   // sqrt(512)/2 / norm
        float v0 = 1.0f + g0 * inv, v1 = 1.0f + g1 * inv;
        __syncthreads();

        // max
        float mx = fmaxf(v0, v1);
#pragma unroll
        for (int o = 32; o; o >>= 1) mx = fmaxf(mx, __shfl_down(mx, o, 64));
        if (lane == 0) sp[wv] = mx;
        __syncthreads();
        if (t == 0) sp[8] = fmaxf(fmaxf(sp[0], sp[1]), fmaxf(sp[2], sp[3]));
        __syncthreads();
        float m = sp[8];
        float e0 = expf(v0 - m), e1 = expf(v1 - m);
        __syncthreads();

        // sum of exp
        float se = e0 + e1;
#pragma unroll
        for (int o = 32; o; o >>= 1) se += __shfl_down(se, o, 64);
        if (lane == 0) sp[wv] = se;
        __syncthreads();
        if (t == 0) sp[8] = sp[0] + sp[1] + sp[2] + sp[3];
        __syncthreads();
        float is = 1.0f / sp[8];
        mask[(size_t)n * CCH + t] = e0 * is;
        mask[(size_t)n * CCH + t + 256] = e1 * is;
    }
}

// K4: out = feat * mask[channel]. One f32x4 per thread.
// Regular loads (feat should be L3-resident from K1); nontemporal stores so the
// 205 MB of output writes don't evict feat from the Infinity Cache mid-kernel.
__global__ __launch_bounds__(256) void k_apply(const float* __restrict__ feat,
                                               const float* __restrict__ mask,
                                               float* __restrict__ out) {
    unsigned int i = blockIdx.x * 256u + threadIdx.x;   // f32x4 index, < TOT4
    unsigned int ch = i / 196u;                         // 784/4 f32x4 per channel
    float m = mask[ch];
    f32x4 v = reinterpret_cast<const f32x4*>(feat)[i];
    v.x *= m; v.y *= m; v.z *= m; v.w *= m;
    __builtin_nontemporal_store(v, reinterpret_cast<f32x4*>(out) + i);
}

extern "C" void kernel_launch(void* const* d_in, const int* in_sizes, int n_in,
                              void* d_out, int out_size, void* d_ws, size_t ws_size,
                              hipStream_t stream) {
    const float* feat = (const float*)d_in[0];
    const int*   y    = (const int*)d_in[1];
    const float* w    = (const float*)d_in[2];
    const float* b    = (const float*)d_in[3];

    float* out_feat = (float*)d_out;                       // 128*512*28*28
    float* out_pred = out_feat + (size_t)NB * CCH * HW;    // 128*1000

    float* pooled = (float*)d_ws;                          // 65536 floats
    float* maskp  = pooled + NB * CCH;                     // 65536 floats

    k_pool <<<(NB * CCH) / 4, 256, 0, stream>>>(feat, pooled);
    k_head <<<LIN_BLOCKS + NB, 256, 0, stream>>>(pooled, w, b, y, out_pred, maskp);
    k_apply<<<TOT4 / 256, 256, 0, stream>>>(feat, maskp, out_feat);
}